// Round 24
// baseline (143.223 us; speedup 1.0000x reference)
//
#include <hip/hip_runtime.h>
#include <hip/hip_bf16.h>

// GIPAConv: N=50000 nodes, E=800000 edges, F_NODE=128, F_EDGE=8, H_ATT=64, H=8, P=16
#define NODECAP 48       // per-node edge cap (deg ~ Poisson(16); passed r2-r23)
#define NPB 256          // nodes per coarse bucket (partition granularity)
#define BCAP 4608        // edges per region (mean 4082 -> +8 sigma)
#define MAXBUCK 256      // LDS bound (nbuck = 196)
#define PART_CHUNK 1600  // edges per partition block (500 blocks -> ~98K global atomics)
#define EPART_BLOCKS 500 // role-split: first 500 blocks of edge_part partition
#define SLICES 8         // 32-node agg slices (r18 optimum)

typedef __attribute__((ext_vector_type(8))) short bf16x8;
typedef __attribute__((ext_vector_type(4))) float f32x4;

static __device__ __forceinline__ short f2b(float f) {
    __hip_bfloat16 h = __float2bfloat16(f);
    return *reinterpret_cast<short*>(&h);
}
static __device__ __forceinline__ float b2f(unsigned short u) {
    union { unsigned int i; float f; } v; v.i = ((unsigned int)u) << 16; return v.f;
}

// pack weights to bf16 [col][k] B-fragment layout; also zero gcnt[nbuck]
__global__ __launch_bounds__(256) void pack_w(
    const float* __restrict__ w_ps, const float* __restrict__ w_pd,
    const float* __restrict__ w_as0, const float* __restrict__ w_ad0,
    short* __restrict__ wp, short* __restrict__ wa, int* __restrict__ gcnt, int nbuck)
{
    const int idx = blockIdx.x * 256 + threadIdx.x;
    if (idx < 256 * 128) {
        const int c = idx >> 7, k = idx & 127;
        const float v = (c < 128) ? w_ps[(size_t)k * 128 + c] : w_pd[(size_t)k * 128 + (c - 128)];
        wp[idx] = f2b(v);
    } else if (idx < 256 * 128 + 128 * 128) {
        const int j = idx - 256 * 128;
        const int c = j >> 7, k = j & 127;
        const float v = (c < 64) ? w_as0[(size_t)k * 64 + c] : w_ad0[(size_t)k * 64 + (c - 64)];
        wa[j] = f2b(v);
    }
    if (idx < nbuck) gcnt[idx] = 0;
}

// r24: 64 nodes per block, SYNC-MINIMAL schedule (r23 diagnosis: node is barrier-stall
// dominated — 4 syncs/block at 32-row tiles; should be ~12us of actual work).
// Order: stage -> [prop MFMA ; hidden MFMA ; ht writes] -> atomicMax -> ONE sync ->
// [quant-stage ; phase3 ; scale] -> sync -> coalesced dumps. LDS aliased: pdtile reuses
// afb's 16KB after the last MFMA read; total 41.4KB (3 blocks/CU).
__global__ __launch_bounds__(256) void node_mfma(
    const float* __restrict__ feat,
    const short* __restrict__ wp, const short* __restrict__ wa,
    const float* __restrict__ b_ps, const float* __restrict__ b_pd,
    const float* __restrict__ w_as1, const float* __restrict__ w_ad1,
    signed char* __restrict__ prop_i8, float* __restrict__ scale_g,
    short* __restrict__ pd_bf,
    short* __restrict__ a_src_bf, float* __restrict__ a_dst, int n)
{
    // smraw layout: [0,16384) afb (feat bf16, swizzled)  -> later ALIASED as pdtile
    //               [16384, 33920) ht[64][137] bf16
    //               [33920, 42112) qtile[64][128] int8
    __shared__ __align__(16) char smraw[42112];
    __shared__ int rowmax_i[64];
    unsigned char* afb = (unsigned char*)smraw;
    short* ht = (short*)(smraw + 16384);
    short* pdtile = (short*)smraw;                       // alias of afb (used post-MFMA)
    signed char* qtile = (signed char*)(smraw + 33920);

    const int t = threadIdx.x;
    const int lane = t & 63;
    const int wid = t >> 6;                   // wave 0..3
    const int l15 = lane & 15;
    const int l4 = lane >> 4;                 // 0..3
    const int base = blockIdx.x * 64;

    if (t < 64) rowmax_i[t] = 0;

    // ---- stage feat (f32) -> bf16 LDS, swizzled ----
    #pragma unroll
    for (int i = 0; i < 4; ++i) {
        const int chunk = t + i * 256;        // 0..1023 = 64 rows x 16 chunks of 8 bf16
        const int row = chunk >> 4;
        const int kc = chunk & 15;
        const int grow = base + row;
        float f[8];
        if (grow < n) {
            const float4 v0 = *reinterpret_cast<const float4*>(feat + (size_t)grow * 128 + kc * 8);
            const float4 v1 = *reinterpret_cast<const float4*>(feat + (size_t)grow * 128 + kc * 8 + 4);
            f[0] = v0.x; f[1] = v0.y; f[2] = v0.z; f[3] = v0.w;
            f[4] = v1.x; f[5] = v1.y; f[6] = v1.z; f[7] = v1.w;
        } else {
            #pragma unroll
            for (int j = 0; j < 8; ++j) f[j] = 0.f;
        }
        short h8[8];
        #pragma unroll
        for (int j = 0; j < 8; ++j) h8[j] = f2b(f[j]);
        const int byte = (row * 256 + kc * 16) ^ ((row & 7) << 4);
        *reinterpret_cast<bf16x8*>(afb + byte) = *reinterpret_cast<const bf16x8*>(h8);
    }
    __syncthreads();                          // sync #1: feat staged

    // ---- prop MFMA: wave owns 4 col-tiles (of 256 cols), 4 row-tiles ----
    f32x4 acc_p[4][4] = {};
    for (int kk = 0; kk < 4; ++kk) {
        bf16x8 a[4], b[4];
        #pragma unroll
        for (int rt = 0; rt < 4; ++rt) {
            const int arow = rt * 16 + l15;
            const int ab = (arow * 256 + kk * 64 + l4 * 16) ^ ((arow & 7) << 4);
            a[rt] = *reinterpret_cast<const bf16x8*>(afb + ab);
        }
        #pragma unroll
        for (int c = 0; c < 4; ++c) {
            const int col = (wid * 4 + c) * 16 + l15;
            b[c] = *reinterpret_cast<const bf16x8*>(wp + (size_t)col * 128 + kk * 32 + l4 * 8);
        }
        #pragma unroll
        for (int rt = 0; rt < 4; ++rt)
            #pragma unroll
            for (int c = 0; c < 4; ++c)
                acc_p[rt][c] = __builtin_amdgcn_mfma_f32_16x16x32_bf16(a[rt], b[c], acc_p[rt][c], 0, 0, 0);
    }

    // ---- hidden MFMA: wave owns 2 col-tiles (of 128 cols), 4 row-tiles ----
    {
        f32x4 acc_h[4][2] = {};
        for (int kk = 0; kk < 4; ++kk) {
            bf16x8 a[4], b[2];
            #pragma unroll
            for (int rt = 0; rt < 4; ++rt) {
                const int arow = rt * 16 + l15;
                const int ab = (arow * 256 + kk * 64 + l4 * 16) ^ ((arow & 7) << 4);
                a[rt] = *reinterpret_cast<const bf16x8*>(afb + ab);
            }
            #pragma unroll
            for (int c = 0; c < 2; ++c) {
                const int col = (wid * 2 + c) * 16 + l15;
                b[c] = *reinterpret_cast<const bf16x8*>(wa + (size_t)col * 128 + kk * 32 + l4 * 8);
            }
            #pragma unroll
            for (int rt = 0; rt < 4; ++rt)
                #pragma unroll
                for (int c = 0; c < 2; ++c)
                    acc_h[rt][c] = __builtin_amdgcn_mfma_f32_16x16x32_bf16(a[rt], b[c], acc_h[rt][c], 0, 0, 0);
        }
        // write relu hidden to ht (does NOT alias afb -> safe before the barrier)
        #pragma unroll
        for (int c = 0; c < 2; ++c) {
            const int col = (wid * 2 + c) * 16 + l15;
            #pragma unroll
            for (int rt = 0; rt < 4; ++rt)
                #pragma unroll
                for (int r = 0; r < 4; ++r)
                    ht[(rt * 16 + l4 * 4 + r) * 137 + col] = f2b(fmaxf(acc_h[rt][c][r], 0.f));
        }
    }

    // per-row absmax of src cols (waves 0-1 own cols 0..127), incl. bias
    if (wid < 2) {
        #pragma unroll
        for (int rt = 0; rt < 4; ++rt)
            #pragma unroll
            for (int r = 0; r < 4; ++r) {
                float m = 0.f;
                #pragma unroll
                for (int c = 0; c < 4; ++c) {
                    const int col = (wid * 4 + c) * 16 + l15;
                    m = fmaxf(m, fabsf(acc_p[rt][c][r] + b_ps[col]));
                }
                atomicMax(&rowmax_i[rt * 16 + l4 * 4 + r], __float_as_int(m));
            }
    }
    __syncthreads();                          // sync #2: MFMA reads of afb done; rowmax done; ht done

    // ---- epilogue: quant-stage (qtile/pdtile, pdtile aliases afb) + phase3 + scale ----
    #pragma unroll
    for (int c = 0; c < 4; ++c) {
        const int col = (wid * 4 + c) * 16 + l15;
        const bool sr = (col < 128);
        const float bias = sr ? b_ps[col] : b_pd[col - 128];
        #pragma unroll
        for (int rt = 0; rt < 4; ++rt)
            #pragma unroll
            for (int r = 0; r < 4; ++r) {
                const int rl = rt * 16 + l4 * 4 + r;
                const float v = acc_p[rt][c][r] + bias;
                if (sr) {
                    const float rm = __int_as_float(rowmax_i[rl]);
                    const float inv = 127.f / fmaxf(rm, 1e-20f);
                    qtile[rl * 128 + col] = (signed char)lrintf(v * inv);
                } else {
                    pdtile[rl * 128 + (col - 128)] = f2b(v);
                }
            }
    }
    if (t < 64) {
        const int row = base + t;
        if (row < n)
            scale_g[row] = fmaxf(__int_as_float(rowmax_i[t]), 1e-20f) / 127.f;
    }

    // phase 3: a_src (bf16) / a_dst (f32) = hidden @ w1 (64 rows x 16 outputs)
    #pragma unroll
    for (int o = 0; o < 4; ++o) {
        const int idx = t + o * 256;          // 0..1023
        const int i = idx >> 4;               // row 0..63
        const int hh = idx & 15;
        const bool is_src = (hh < 8);
        const int h = is_src ? hh : (hh - 8);
        const float* w1 = is_src ? w_as1 : w_ad1;
        const int jb = is_src ? 0 : 64;
        float acc = 0.f;
        #pragma unroll
        for (int j = 0; j < 64; ++j)
            acc += b2f((unsigned short)ht[i * 137 + jb + j]) * w1[j * 8 + h];
        const int row = base + i;
        if (row < n) {
            if (is_src) a_src_bf[(size_t)row * 8 + h] = f2b(acc);
            else        a_dst[(size_t)row * 8 + h] = acc;
        }
    }
    __syncthreads();                          // sync #3: tiles staged

    // ---- coalesced dumps ----
    // qtile: 64 rows x 128B = 512 x 16B segs -> 2 iters
    #pragma unroll
    for (int i = 0; i < 2; ++i) {
        const int idx = t + i * 256;
        const int row = idx >> 3, seg = idx & 7;
        const int grow = base + row;
        if (grow < n)
            *reinterpret_cast<int4*>(prop_i8 + (size_t)grow * 128 + seg * 16) =
                *reinterpret_cast<const int4*>(qtile + row * 128 + seg * 16);
    }
    // pdtile: 64 rows x 256B = 1024 x 16B segs -> 4 iters
    #pragma unroll
    for (int i = 0; i < 4; ++i) {
        const int idx = t + i * 256;
        const int row = idx >> 4, seg = idx & 15;
        const int grow = base + row;
        if (grow < n)
            *reinterpret_cast<int4*>(pd_bf + (size_t)grow * 128 + seg * 8) =
                *reinterpret_cast<const int4*>(pdtile + row * 128 + seg * 8);
    }
}

// Role-split edge kernel. Blocks [0, EPART_BLOCKS): partition (LDS histogram -> one
// global atomic per (block,bucket), ~98K total -> LDS-cursor scatter). Blocks
// [EPART_BLOCKS, ...): per-edge MLP + a_src gather -> ax (bf16).
__global__ __launch_bounds__(256) void edge_part(
    const int* __restrict__ src, const int* __restrict__ dst,
    const float* __restrict__ feat_edge,
    const float* __restrict__ w_e0, const float* __restrict__ w_e1,
    const short* __restrict__ a_src_bf,
    int* __restrict__ gcnt, int2* __restrict__ part, short* __restrict__ ax,
    int E, int nbuck)
{
    __shared__ int hist[MAXBUCK];
    __shared__ int cursor[MAXBUCK];
    __shared__ int dcache[PART_CHUNK];
    const int t = threadIdx.x;

    if (blockIdx.x < EPART_BLOCKS) {
        const int e0 = blockIdx.x * PART_CHUNK;
        const int e1 = min(e0 + PART_CHUNK, E);

        for (int i = t; i < nbuck; i += 256) hist[i] = 0;
        __syncthreads();
        for (int e = e0 + t; e < e1; e += 256) {
            const int d = dst[e];
            dcache[e - e0] = d;
            atomicAdd(&hist[d >> 8], 1);
        }
        __syncthreads();
        for (int i = t; i < nbuck; i += 256) {
            const int c = hist[i];
            cursor[i] = (c > 0) ? atomicAdd(&gcnt[i], c) : 0;
        }
        __syncthreads();
        for (int e = e0 + t; e < e1; e += 256) {
            const int d = dcache[e - e0];
            const int s = src[e];
            const int b = d >> 8;
            const int pos = atomicAdd(&cursor[b], 1);
            if (pos < BCAP)
                part[(size_t)b * BCAP + pos] = make_int2((e << 8) | (d & 255), s);
        }
        return;
    }

    const int e = (blockIdx.x - EPART_BLOCKS) * 256 + t;
    if (e >= E) return;

    float fe[8];
    const float4 v0 = *reinterpret_cast<const float4*>(feat_edge + (size_t)e * 8);
    const float4 v1 = *reinterpret_cast<const float4*>(feat_edge + (size_t)e * 8 + 4);
    fe[0] = v0.x; fe[1] = v0.y; fe[2] = v0.z; fe[3] = v0.w;
    fe[4] = v1.x; fe[5] = v1.y; fe[6] = v1.z; fe[7] = v1.w;

    // tiny MLP: weight indices thread-uniform -> scalar loads
    float ae[8] = {};
    #pragma unroll 8
    for (int j = 0; j < 64; ++j) {
        float hj = 0.f;
        #pragma unroll
        for (int k = 0; k < 8; ++k) hj += fe[k] * w_e0[k * 64 + j];
        hj = fmaxf(hj, 0.f);
        #pragma unroll
        for (int hh = 0; hh < 8; ++hh) ae[hh] += hj * w_e1[j * 8 + hh];
    }

    const int s = src[e];
    const ushort4 as0 = *reinterpret_cast<const ushort4*>(a_src_bf + (size_t)s * 8);
    const ushort4 as1 = *reinterpret_cast<const ushort4*>(a_src_bf + (size_t)s * 8 + 4);
    short eb[8];
    eb[0] = f2b(ae[0] + b2f(as0.x)); eb[1] = f2b(ae[1] + b2f(as0.y));
    eb[2] = f2b(ae[2] + b2f(as0.z)); eb[3] = f2b(ae[3] + b2f(as0.w));
    eb[4] = f2b(ae[4] + b2f(as1.x)); eb[5] = f2b(ae[5] + b2f(as1.y));
    eb[6] = f2b(ae[6] + b2f(as1.z)); eb[7] = f2b(ae[7] + b2f(as1.w));
    *reinterpret_cast<uint4*>(ax + (size_t)e * 8) = *reinterpret_cast<const uint4*>(eb);
}

// Block = one 32-node slice of a 256-node coarse bucket, LINEAR grid.
// 16-LANE groups (h = l>>1, 8 int8 elems/lane): a full 128B prop row per 16 lanes ->
// wave64 carries 4 edges per memory instruction (r22 lever). 8-deep batching; in-loop
// denominator; out = pd(prefetched) + agg via nontemporal store.
__global__ __launch_bounds__(256) void bucket_agg(
    const int2* __restrict__ part, const int* __restrict__ gcnt,
    const short* __restrict__ ax, const float* __restrict__ a_dst,
    const signed char* __restrict__ prop_i8, const float* __restrict__ scale_g,
    const short* __restrict__ pd_bf,
    float* __restrict__ out, int n)
{
    __shared__ int2  lists[32][NODECAP];  // (e, s)  12 KB
    __shared__ int   lcnt[32];
    __shared__ float adst_s[32][8];       // 1 KB
    const int t = threadIdx.x;
    const int b = blockIdx.x >> 3;        // coarse bucket
    const int slice = blockIdx.x & 7;     // 32-node slice
    const int node0 = (b << 8) + (slice << 5);

    if (t < 32) lcnt[t] = 0;
    {
        const int r = t >> 3, h = t & 7;  // t covers 32*8 = 256 exactly
        const int nd = node0 + r;
        adst_s[r][h] = (nd < n) ? a_dst[(size_t)nd * 8 + h] : 0.f;
    }
    __syncthreads();

    const int cnt = min(gcnt[b], BCAP);
    const int2* pb = part + (size_t)b * BCAP;
    for (int j = t; j < cnt; j += 256) {
        const int2 pr = pb[j];
        const int dlow = pr.x & 255;
        if ((dlow >> 5) == slice) {
            const int r = dlow & 31;
            const int slot = atomicAdd(&lcnt[r], 1);
            if (slot < NODECAP) lists[r][slot] = make_int2(pr.x >> 8, pr.y); // (e, s)
        }
    }
    __syncthreads();

    const int grp = t >> 4;               // 16 groups of 16 lanes
    const int l = t & 15;
    const int h = l >> 1;                 // head 0..7
    const int half = l & 1;               // half-row: elements h*16 + half*8 + 0..7
    const int eoff = h * 16 + half * 8;

    union I2C { int2 i; signed char c[8]; };

    for (int r = grp; r < 32; r += 16) {
        const int node = node0 + r;
        if (node >= n) continue;
        int deg = lcnt[r];
        if (deg > NODECAP) deg = NODECAP;
        const float adv = adst_s[r][h];

        // prefetch the residual early (8 bf16 = two 8B loads); hides under the gather loop
        const ushort4 pda = *reinterpret_cast<const ushort4*>(
            pd_bf + (size_t)node * 128 + eoff);
        const ushort4 pdb = *reinterpret_cast<const ushort4*>(
            pd_bf + (size_t)node * 128 + eoff + 4);

        float dsumv = 0.f;
        float acc[8] = {};
        for (int j0 = 0; j0 < deg; j0 += 8) {
            float at[8]; float sc[8]; I2C pv[8];
            #pragma unroll
            for (int u = 0; u < 8; ++u) {
                const int j = j0 + u;
                const bool act = (j < deg);
                const int2 pr = lists[r][act ? j : 0];   // LDS broadcast across group
                at[u] = b2f((unsigned short)ax[(size_t)pr.x * 8 + h]);
                sc[u] = scale_g[pr.y];                   // 4B broadcast, L2-hot (200KB)
                pv[u].i = *reinterpret_cast<const int2*>(
                    prop_i8 + (size_t)pr.y * 128 + eoff);
            }
            #pragma unroll
            for (int u = 0; u < 8; ++u) {
                const bool act = (j0 + u < deg);
                const float ex = act ? __expf(fmaxf(at[u] + adv, 0.f)) : 0.f;
                dsumv += ex;
                const float exsc = ex * sc[u];           // fold dequant scale into weight
                #pragma unroll
                for (int k = 0; k < 8; ++k)
                    acc[k] += exsc * (float)pv[u].c[k];
            }
        }
        const float dinv = 1.f / fmaxf(dsumv, 1e-16f);

        f32x4 o0, o1;
        o0[0] = b2f(pda.x) + acc[0] * dinv; o0[1] = b2f(pda.y) + acc[1] * dinv;
        o0[2] = b2f(pda.z) + acc[2] * dinv; o0[3] = b2f(pda.w) + acc[3] * dinv;
        o1[0] = b2f(pdb.x) + acc[4] * dinv; o1[1] = b2f(pdb.y) + acc[5] * dinv;
        o1[2] = b2f(pdb.z) + acc[6] * dinv; o1[3] = b2f(pdb.w) + acc[7] * dinv;
        // nontemporal: out is written once, never re-read — keep L2 for prop_i8
        float* op = out + (size_t)node * 128 + eoff;
        __builtin_nontemporal_store(o0, reinterpret_cast<f32x4*>(op));
        __builtin_nontemporal_store(o1, reinterpret_cast<f32x4*>(op + 4));
    }
}

extern "C" void kernel_launch(void* const* d_in, const int* in_sizes, int n_in,
                              void* d_out, int out_size, void* d_ws, size_t ws_size,
                              hipStream_t stream)
{
    const float* feat      = (const float*)d_in[0];
    const float* feat_edge = (const float*)d_in[1];
    const int*   src       = (const int*)d_in[2];
    const int*   dst       = (const int*)d_in[3];
    const float* w_as0     = (const float*)d_in[4];
    const float* w_as1     = (const float*)d_in[5];
    const float* w_ad0     = (const float*)d_in[6];
    const float* w_ad1     = (const float*)d_in[7];
    const float* w_e0      = (const float*)d_in[8];
    const float* w_e1      = (const float*)d_in[9];
    const float* w_ps      = (const float*)d_in[10];
    const float* b_ps      = (const float*)d_in[11];
    const float* w_pd      = (const float*)d_in[12];
    const float* b_pd      = (const float*)d_in[13];

    const int n = in_sizes[0] / 128;   // 50000
    const int E = in_sizes[2];         // 800000
    const int nbuck = (n + NPB - 1) / NPB;   // 196
    float* out = (float*)d_out;

    // workspace layout (~42 MB):
    //   prop_i8[n*128] i8 | scale_g[n] f32 | pd_bf[n*128] bf16 | a_src_bf[n*8] bf16 |
    //   a_dst[n*8] f32 | gcnt i32 | part[nbuck*BCAP] int2 | ax[E*8] bf16 | wp | wa
    signed char* prop_i8 = (signed char*)d_ws;
    float* scale_g = (float*)(prop_i8 + (size_t)n * 128);
    short* pd_bf   = (short*)(scale_g + n);
    short* a_src_bf = pd_bf + (size_t)n * 128;
    float* a_dst = (float*)(a_src_bf + (size_t)n * 8);
    int*   gcnt  = (int*)(a_dst + (size_t)n * 8);
    int2*  part  = (int2*)(gcnt + ((nbuck + 1) & ~1));
    short* ax    = (short*)(part + (size_t)nbuck * BCAP);
    short* wp    = ax + (size_t)E * 8;
    short* wa    = wp + 256 * 128;

    pack_w<<<192, 256, 0, stream>>>(
        w_ps, w_pd, w_as0, w_ad0, wp, wa, gcnt, nbuck);

    node_mfma<<<(n + 63) / 64, 256, 0, stream>>>(
        feat, wp, wa, b_ps, b_pd, w_as1, w_ad1,
        prop_i8, scale_g, pd_bf, a_src_bf, a_dst, n);

    const int axBlocks = (E + 255) / 256;   // 3125
    edge_part<<<EPART_BLOCKS + axBlocks, 256, 0, stream>>>(
        src, dst, feat_edge, w_e0, w_e1, a_src_bf, gcnt, part, ax, E, nbuck);

    bucket_agg<<<nbuck * SLICES, 256, 0, stream>>>(
        part, gcnt, ax, a_dst, prop_i8, scale_g, pd_bf, out, n);
}

// Round 25
// 127.445 us; speedup vs baseline: 1.1238x; 1.1238x over previous
//
#include <hip/hip_runtime.h>
#include <hip/hip_bf16.h>

// GIPAConv: N=50000 nodes, E=800000 edges, F_NODE=128, F_EDGE=8, H_ATT=64, H=8, P=16
#define NODECAP 48       // per-node edge cap (deg ~ Poisson(16); passed r2-r24)
#define NPB 256          // nodes per coarse bucket (partition granularity)
#define BCAP 4608        // edges per region (mean 4082 -> +8 sigma)
#define MAXBUCK 256      // LDS bound (nbuck = 196)
#define PART_CHUNK 1600  // edges per partition block (500 blocks -> ~98K global atomics)
#define EPART_BLOCKS 500 // role-split: first 500 blocks of edge_part partition
#define SLICES 8         // 32-node agg slices (r18 optimum)

typedef __attribute__((ext_vector_type(8))) short bf16x8;
typedef __attribute__((ext_vector_type(4))) float f32x4;

static __device__ __forceinline__ short f2b(float f) {
    __hip_bfloat16 h = __float2bfloat16(f);
    return *reinterpret_cast<short*>(&h);
}
static __device__ __forceinline__ float b2f(unsigned short u) {
    union { unsigned int i; float f; } v; v.i = ((unsigned int)u) << 16; return v.f;
}

// pack weights to bf16 [col][k] B-fragment layout; r25: also pack wb = block-diagonal
// [w_as1 | w_ad1] as 16 cols x 128 k (zeros off-block -> full-K MFMA sum is exact);
// also zero gcnt[nbuck]
__global__ __launch_bounds__(256) void pack_w(
    const float* __restrict__ w_ps, const float* __restrict__ w_pd,
    const float* __restrict__ w_as0, const float* __restrict__ w_ad0,
    const float* __restrict__ w_as1, const float* __restrict__ w_ad1,
    short* __restrict__ wp, short* __restrict__ wa, short* __restrict__ wb,
    int* __restrict__ gcnt, int nbuck)
{
    const int idx = blockIdx.x * 256 + threadIdx.x;
    if (idx < 256 * 128) {
        const int c = idx >> 7, k = idx & 127;
        const float v = (c < 128) ? w_ps[(size_t)k * 128 + c] : w_pd[(size_t)k * 128 + (c - 128)];
        wp[idx] = f2b(v);
    } else if (idx < 256 * 128 + 128 * 128) {
        const int j = idx - 256 * 128;
        const int c = j >> 7, k = j & 127;
        const float v = (c < 64) ? w_as0[(size_t)k * 64 + c] : w_ad0[(size_t)k * 64 + (c - 64)];
        wa[j] = f2b(v);
    } else if (idx < 256 * 128 + 128 * 128 + 16 * 128) {
        const int j = idx - (256 * 128 + 128 * 128);
        const int c = j >> 7, k = j & 127;
        float v = 0.f;
        if (c < 8)  { if (k < 64)  v = w_as1[(size_t)k * 8 + c]; }
        else        { if (k >= 64) v = w_ad1[(size_t)(k - 64) * 8 + (c - 8)]; }
        wb[j] = f2b(v);
    }
    if (idx < nbuck) gcnt[idx] = 0;
}

// 32 nodes per block, 4 waves, MFMA 16x16x32 bf16 (r23 structure = measured best).
// r25: phase 3 ([a_src|a_dst] = ht @ wb) is now an MFMA chain on waves 0-1 instead of a
// serial 64-iter per-thread loop (r24 diagnosis: phase 3's ~130K issue-slots/block were
// node's invariant ~20us cost across every tile/sync variant).
__global__ __launch_bounds__(256) void node_mfma(
    const float* __restrict__ feat,
    const short* __restrict__ wp, const short* __restrict__ wa, const short* __restrict__ wb,
    const float* __restrict__ b_ps, const float* __restrict__ b_pd,
    signed char* __restrict__ prop_i8, float* __restrict__ scale_g,
    short* __restrict__ pd_bf,
    short* __restrict__ a_src_bf, float* __restrict__ a_dst, int n)
{
    __shared__ unsigned char afb[32 * 256];   // 8 KB: feat tile bf16, XOR-swizzled (T2)
    __shared__ short ht[32][136];             // 8.5 KB: relu hidden bf16; stride 272B keeps
                                              // 16B-aligned A-frag reads (2-way bank alias, free)
    __shared__ signed char qtile[32][128];    // 4 KB: staged int8 prop tile
    __shared__ short pdtile[32][128];         // 8 KB: staged bf16 pd tile
    __shared__ int rowmax_i[32];              // per-row |max| for int8 quant (f32 as int)
    const int t = threadIdx.x;
    const int lane = t & 63;
    const int wid = t >> 6;                   // wave 0..3
    const int l15 = lane & 15;
    const int l4 = lane >> 4;                 // 0..3
    const int base = blockIdx.x * 32;

    if (t < 32) rowmax_i[t] = 0;

    // ---- stage feat (f32) -> bf16 LDS, swizzled ----
    #pragma unroll
    for (int i = 0; i < 2; ++i) {
        const int chunk = t + i * 256;        // 0..511 = 32 rows x 16 chunks of 8 bf16
        const int row = chunk >> 4;
        const int kc = chunk & 15;
        const int grow = base + row;
        float f[8];
        if (grow < n) {
            const float4 v0 = *reinterpret_cast<const float4*>(feat + (size_t)grow * 128 + kc * 8);
            const float4 v1 = *reinterpret_cast<const float4*>(feat + (size_t)grow * 128 + kc * 8 + 4);
            f[0] = v0.x; f[1] = v0.y; f[2] = v0.z; f[3] = v0.w;
            f[4] = v1.x; f[5] = v1.y; f[6] = v1.z; f[7] = v1.w;
        } else {
            #pragma unroll
            for (int j = 0; j < 8; ++j) f[j] = 0.f;
        }
        short h8[8];
        #pragma unroll
        for (int j = 0; j < 8; ++j) h8[j] = f2b(f[j]);
        const int byte = (row * 256 + kc * 16) ^ ((row & 7) << 4);
        *reinterpret_cast<bf16x8*>(afb + byte) = *reinterpret_cast<const bf16x8*>(h8);
    }
    __syncthreads();

    // ---- prop = feat @ [w_ps|w_pd] : wave owns 4 col-tiles, 2 row-tiles ----
    {
        f32x4 acc[2][4] = {};
        for (int kk = 0; kk < 4; ++kk) {
            bf16x8 a[2], b[4];
            #pragma unroll
            for (int rt = 0; rt < 2; ++rt) {
                const int arow = rt * 16 + l15;
                const int ab = (arow * 256 + kk * 64 + l4 * 16) ^ ((arow & 7) << 4);
                a[rt] = *reinterpret_cast<const bf16x8*>(afb + ab);
            }
            #pragma unroll
            for (int c = 0; c < 4; ++c) {
                const int col = (wid * 4 + c) * 16 + l15;
                b[c] = *reinterpret_cast<const bf16x8*>(wp + (size_t)col * 128 + kk * 32 + l4 * 8);
            }
            #pragma unroll
            for (int rt = 0; rt < 2; ++rt)
                #pragma unroll
                for (int c = 0; c < 4; ++c)
                    acc[rt][c] = __builtin_amdgcn_mfma_f32_16x16x32_bf16(a[rt], b[c], acc[rt][c], 0, 0, 0);
        }

        // per-row absmax over src cols (waves 0-1 hold cols 0..127), incl. bias
        if (wid < 2) {
            #pragma unroll
            for (int rt = 0; rt < 2; ++rt)
                #pragma unroll
                for (int r = 0; r < 4; ++r) {
                    float m = 0.f;
                    #pragma unroll
                    for (int c = 0; c < 4; ++c) {
                        const int col = (wid * 4 + c) * 16 + l15;
                        m = fmaxf(m, fabsf(acc[rt][c][r] + b_ps[col]));
                    }
                    atomicMax(&rowmax_i[rt * 16 + l4 * 4 + r], __float_as_int(m));
                }
        }
        __syncthreads();

        // quantize / convert into LDS tiles (no global scatter)
        #pragma unroll
        for (int c = 0; c < 4; ++c) {
            const int col = (wid * 4 + c) * 16 + l15;
            const bool sr = (col < 128);
            const float bias = sr ? b_ps[col] : b_pd[col - 128];
            #pragma unroll
            for (int rt = 0; rt < 2; ++rt)
                #pragma unroll
                for (int r = 0; r < 4; ++r) {
                    const int rl = rt * 16 + l4 * 4 + r;
                    const float v = acc[rt][c][r] + bias;
                    if (sr) {
                        const float rm = __int_as_float(rowmax_i[rl]);
                        const float inv = 127.f / fmaxf(rm, 1e-20f);
                        qtile[rl][col] = (signed char)lrintf(v * inv);
                    } else {
                        pdtile[rl][col - 128] = f2b(v);
                    }
                }
        }
        if (t < 32) {
            const int row = base + t;
            if (row < n)
                scale_g[row] = fmaxf(__int_as_float(rowmax_i[t]), 1e-20f) / 127.f;
        }
        __syncthreads();

        // coalesced dump: prop 4KB = 256 x 16B; pd 8KB = 256 x 32B
        {
            const int row = t >> 3;          // 32 rows, 8 threads/row
            const int seg = t & 7;           // 16B segment within the row
            const int grow = base + row;
            if (grow < n) {
                *reinterpret_cast<int4*>(prop_i8 + (size_t)grow * 128 + seg * 16) =
                    *reinterpret_cast<const int4*>(&qtile[row][seg * 16]);
                *reinterpret_cast<int4*>(pd_bf + (size_t)grow * 128 + seg * 16) =
                    *reinterpret_cast<const int4*>(&pdtile[row][seg * 16]);
                *reinterpret_cast<int4*>(pd_bf + (size_t)grow * 128 + seg * 16 + 8) =
                    *reinterpret_cast<const int4*>(&pdtile[row][seg * 16 + 8]);
            }
        }
    }

    // ---- hidden = relu(feat @ [w_as0|w_ad0]) : wave owns 2 col-tiles, 2 row-tiles ----
    {
        f32x4 acc[2][2] = {};
        for (int kk = 0; kk < 4; ++kk) {
            bf16x8 a[2], b[2];
            #pragma unroll
            for (int rt = 0; rt < 2; ++rt) {
                const int arow = rt * 16 + l15;
                const int ab = (arow * 256 + kk * 64 + l4 * 16) ^ ((arow & 7) << 4);
                a[rt] = *reinterpret_cast<const bf16x8*>(afb + ab);
            }
            #pragma unroll
            for (int c = 0; c < 2; ++c) {
                const int col = (wid * 2 + c) * 16 + l15;
                b[c] = *reinterpret_cast<const bf16x8*>(wa + (size_t)col * 128 + kk * 32 + l4 * 8);
            }
            #pragma unroll
            for (int rt = 0; rt < 2; ++rt)
                #pragma unroll
                for (int c = 0; c < 2; ++c)
                    acc[rt][c] = __builtin_amdgcn_mfma_f32_16x16x32_bf16(a[rt], b[c], acc[rt][c], 0, 0, 0);
        }
        #pragma unroll
        for (int c = 0; c < 2; ++c) {
            const int col = (wid * 2 + c) * 16 + l15;
            #pragma unroll
            for (int rt = 0; rt < 2; ++rt)
                #pragma unroll
                for (int r = 0; r < 4; ++r)
                    ht[rt * 16 + l4 * 4 + r][col] = f2b(fmaxf(acc[rt][c][r], 0.f));
        }
    }
    __syncthreads();

    // ---- phase 3 (MFMA): [a_src|a_dst] = ht @ wb, block-diagonal 128x16.
    // Waves 0-1 each own one 16-row tile: 4 K-step MFMAs replace the serial loop.
    if (wid < 2) {
        const int rt = wid;
        f32x4 acc3 = {};
        for (int kk = 0; kk < 4; ++kk) {
            const bf16x8 a = *reinterpret_cast<const bf16x8*>(
                &ht[rt * 16 + l15][kk * 32 + l4 * 8]);
            const bf16x8 b = *reinterpret_cast<const bf16x8*>(
                wb + l15 * 128 + kk * 32 + l4 * 8);
            acc3 = __builtin_amdgcn_mfma_f32_16x16x32_bf16(a, b, acc3, 0, 0, 0);
        }
        // C layout: col = l15 (head: <8 src, >=8 dst), row = l4*4 + r within tile
        #pragma unroll
        for (int r = 0; r < 4; ++r) {
            const int grow = base + rt * 16 + l4 * 4 + r;
            if (grow < n) {
                if (l15 < 8) a_src_bf[(size_t)grow * 8 + l15] = f2b(acc3[r]);
                else         a_dst[(size_t)grow * 8 + (l15 - 8)] = acc3[r];
            }
        }
    }
}

// Role-split edge kernel. Blocks [0, EPART_BLOCKS): partition (LDS histogram -> one
// global atomic per (block,bucket), ~98K total -> LDS-cursor scatter). Blocks
// [EPART_BLOCKS, ...): per-edge MLP + a_src gather -> ax (bf16).
__global__ __launch_bounds__(256) void edge_part(
    const int* __restrict__ src, const int* __restrict__ dst,
    const float* __restrict__ feat_edge,
    const float* __restrict__ w_e0, const float* __restrict__ w_e1,
    const short* __restrict__ a_src_bf,
    int* __restrict__ gcnt, int2* __restrict__ part, short* __restrict__ ax,
    int E, int nbuck)
{
    __shared__ int hist[MAXBUCK];
    __shared__ int cursor[MAXBUCK];
    __shared__ int dcache[PART_CHUNK];
    const int t = threadIdx.x;

    if (blockIdx.x < EPART_BLOCKS) {
        const int e0 = blockIdx.x * PART_CHUNK;
        const int e1 = min(e0 + PART_CHUNK, E);

        for (int i = t; i < nbuck; i += 256) hist[i] = 0;
        __syncthreads();
        for (int e = e0 + t; e < e1; e += 256) {
            const int d = dst[e];
            dcache[e - e0] = d;
            atomicAdd(&hist[d >> 8], 1);
        }
        __syncthreads();
        for (int i = t; i < nbuck; i += 256) {
            const int c = hist[i];
            cursor[i] = (c > 0) ? atomicAdd(&gcnt[i], c) : 0;
        }
        __syncthreads();
        for (int e = e0 + t; e < e1; e += 256) {
            const int d = dcache[e - e0];
            const int s = src[e];
            const int b = d >> 8;
            const int pos = atomicAdd(&cursor[b], 1);
            if (pos < BCAP)
                part[(size_t)b * BCAP + pos] = make_int2((e << 8) | (d & 255), s);
        }
        return;
    }

    const int e = (blockIdx.x - EPART_BLOCKS) * 256 + t;
    if (e >= E) return;

    float fe[8];
    const float4 v0 = *reinterpret_cast<const float4*>(feat_edge + (size_t)e * 8);
    const float4 v1 = *reinterpret_cast<const float4*>(feat_edge + (size_t)e * 8 + 4);
    fe[0] = v0.x; fe[1] = v0.y; fe[2] = v0.z; fe[3] = v0.w;
    fe[4] = v1.x; fe[5] = v1.y; fe[6] = v1.z; fe[7] = v1.w;

    // tiny MLP: weight indices thread-uniform -> scalar loads
    float ae[8] = {};
    #pragma unroll 8
    for (int j = 0; j < 64; ++j) {
        float hj = 0.f;
        #pragma unroll
        for (int k = 0; k < 8; ++k) hj += fe[k] * w_e0[k * 64 + j];
        hj = fmaxf(hj, 0.f);
        #pragma unroll
        for (int hh = 0; hh < 8; ++hh) ae[hh] += hj * w_e1[j * 8 + hh];
    }

    const int s = src[e];
    const ushort4 as0 = *reinterpret_cast<const ushort4*>(a_src_bf + (size_t)s * 8);
    const ushort4 as1 = *reinterpret_cast<const ushort4*>(a_src_bf + (size_t)s * 8 + 4);
    short eb[8];
    eb[0] = f2b(ae[0] + b2f(as0.x)); eb[1] = f2b(ae[1] + b2f(as0.y));
    eb[2] = f2b(ae[2] + b2f(as0.z)); eb[3] = f2b(ae[3] + b2f(as0.w));
    eb[4] = f2b(ae[4] + b2f(as1.x)); eb[5] = f2b(ae[5] + b2f(as1.y));
    eb[6] = f2b(ae[6] + b2f(as1.z)); eb[7] = f2b(ae[7] + b2f(as1.w));
    *reinterpret_cast<uint4*>(ax + (size_t)e * 8) = *reinterpret_cast<const uint4*>(eb);
}

// Block = one 32-node slice of a 256-node coarse bucket, LINEAR grid.
// 16-LANE groups (h = l>>1, 8 int8 elems/lane): a full 128B prop row per 16 lanes ->
// wave64 carries 4 edges per memory instruction (r22 lever). 8-deep batching; in-loop
// denominator; out = pd(prefetched) + agg via nontemporal store.
__global__ __launch_bounds__(256) void bucket_agg(
    const int2* __restrict__ part, const int* __restrict__ gcnt,
    const short* __restrict__ ax, const float* __restrict__ a_dst,
    const signed char* __restrict__ prop_i8, const float* __restrict__ scale_g,
    const short* __restrict__ pd_bf,
    float* __restrict__ out, int n)
{
    __shared__ int2  lists[32][NODECAP];  // (e, s)  12 KB
    __shared__ int   lcnt[32];
    __shared__ float adst_s[32][8];       // 1 KB
    const int t = threadIdx.x;
    const int b = blockIdx.x >> 3;        // coarse bucket
    const int slice = blockIdx.x & 7;     // 32-node slice
    const int node0 = (b << 8) + (slice << 5);

    if (t < 32) lcnt[t] = 0;
    {
        const int r = t >> 3, h = t & 7;  // t covers 32*8 = 256 exactly
        const int nd = node0 + r;
        adst_s[r][h] = (nd < n) ? a_dst[(size_t)nd * 8 + h] : 0.f;
    }
    __syncthreads();

    const int cnt = min(gcnt[b], BCAP);
    const int2* pb = part + (size_t)b * BCAP;
    for (int j = t; j < cnt; j += 256) {
        const int2 pr = pb[j];
        const int dlow = pr.x & 255;
        if ((dlow >> 5) == slice) {
            const int r = dlow & 31;
            const int slot = atomicAdd(&lcnt[r], 1);
            if (slot < NODECAP) lists[r][slot] = make_int2(pr.x >> 8, pr.y); // (e, s)
        }
    }
    __syncthreads();

    const int grp = t >> 4;               // 16 groups of 16 lanes
    const int l = t & 15;
    const int h = l >> 1;                 // head 0..7
    const int half = l & 1;               // half-row: elements h*16 + half*8 + 0..7
    const int eoff = h * 16 + half * 8;

    union I2C { int2 i; signed char c[8]; };

    for (int r = grp; r < 32; r += 16) {
        const int node = node0 + r;
        if (node >= n) continue;
        int deg = lcnt[r];
        if (deg > NODECAP) deg = NODECAP;
        const float adv = adst_s[r][h];

        // prefetch the residual early (8 bf16 = two 8B loads); hides under the gather loop
        const ushort4 pda = *reinterpret_cast<const ushort4*>(
            pd_bf + (size_t)node * 128 + eoff);
        const ushort4 pdb = *reinterpret_cast<const ushort4*>(
            pd_bf + (size_t)node * 128 + eoff + 4);

        float dsumv = 0.f;
        float acc[8] = {};
        for (int j0 = 0; j0 < deg; j0 += 8) {
            float at[8]; float sc[8]; I2C pv[8];
            #pragma unroll
            for (int u = 0; u < 8; ++u) {
                const int j = j0 + u;
                const bool act = (j < deg);
                const int2 pr = lists[r][act ? j : 0];   // LDS broadcast across group
                at[u] = b2f((unsigned short)ax[(size_t)pr.x * 8 + h]);
                sc[u] = scale_g[pr.y];                   // 4B broadcast, L2-hot (200KB)
                pv[u].i = *reinterpret_cast<const int2*>(
                    prop_i8 + (size_t)pr.y * 128 + eoff);
            }
            #pragma unroll
            for (int u = 0; u < 8; ++u) {
                const bool act = (j0 + u < deg);
                const float ex = act ? __expf(fmaxf(at[u] + adv, 0.f)) : 0.f;
                dsumv += ex;
                const float exsc = ex * sc[u];           // fold dequant scale into weight
                #pragma unroll
                for (int k = 0; k < 8; ++k)
                    acc[k] += exsc * (float)pv[u].c[k];
            }
        }
        const float dinv = 1.f / fmaxf(dsumv, 1e-16f);

        f32x4 o0, o1;
        o0[0] = b2f(pda.x) + acc[0] * dinv; o0[1] = b2f(pda.y) + acc[1] * dinv;
        o0[2] = b2f(pda.z) + acc[2] * dinv; o0[3] = b2f(pda.w) + acc[3] * dinv;
        o1[0] = b2f(pdb.x) + acc[4] * dinv; o1[1] = b2f(pdb.y) + acc[5] * dinv;
        o1[2] = b2f(pdb.z) + acc[6] * dinv; o1[3] = b2f(pdb.w) + acc[7] * dinv;
        // nontemporal: out is written once, never re-read — keep L2 for prop_i8
        float* op = out + (size_t)node * 128 + eoff;
        __builtin_nontemporal_store(o0, reinterpret_cast<f32x4*>(op));
        __builtin_nontemporal_store(o1, reinterpret_cast<f32x4*>(op + 4));
    }
}

extern "C" void kernel_launch(void* const* d_in, const int* in_sizes, int n_in,
                              void* d_out, int out_size, void* d_ws, size_t ws_size,
                              hipStream_t stream)
{
    const float* feat      = (const float*)d_in[0];
    const float* feat_edge = (const float*)d_in[1];
    const int*   src       = (const int*)d_in[2];
    const int*   dst       = (const int*)d_in[3];
    const float* w_as0     = (const float*)d_in[4];
    const float* w_as1     = (const float*)d_in[5];
    const float* w_ad0     = (const float*)d_in[6];
    const float* w_ad1     = (const float*)d_in[7];
    const float* w_e0      = (const float*)d_in[8];
    const float* w_e1      = (const float*)d_in[9];
    const float* w_ps      = (const float*)d_in[10];
    const float* b_ps      = (const float*)d_in[11];
    const float* w_pd      = (const float*)d_in[12];
    const float* b_pd      = (const float*)d_in[13];

    const int n = in_sizes[0] / 128;   // 50000
    const int E = in_sizes[2];         // 800000
    const int nbuck = (n + NPB - 1) / NPB;   // 196
    float* out = (float*)d_out;

    // workspace layout (~42 MB):
    //   prop_i8[n*128] i8 | scale_g[n] f32 | pd_bf[n*128] bf16 | a_src_bf[n*8] bf16 |
    //   a_dst[n*8] f32 | gcnt i32 | part[nbuck*BCAP] int2 | ax[E*8] bf16 | wp | wa | wb
    signed char* prop_i8 = (signed char*)d_ws;
    float* scale_g = (float*)(prop_i8 + (size_t)n * 128);
    short* pd_bf   = (short*)(scale_g + n);
    short* a_src_bf = pd_bf + (size_t)n * 128;
    float* a_dst = (float*)(a_src_bf + (size_t)n * 8);
    int*   gcnt  = (int*)(a_dst + (size_t)n * 8);
    int2*  part  = (int2*)(gcnt + ((nbuck + 1) & ~1));
    short* ax    = (short*)(part + (size_t)nbuck * BCAP);
    short* wp    = ax + (size_t)E * 8;
    short* wa    = wp + 256 * 128;
    short* wb    = wa + 128 * 128;

    pack_w<<<202, 256, 0, stream>>>(
        w_ps, w_pd, w_as0, w_ad0, w_as1, w_ad1, wp, wa, wb, gcnt, nbuck);

    node_mfma<<<(n + 31) / 32, 256, 0, stream>>>(
        feat, wp, wa, wb, b_ps, b_pd,
        prop_i8, scale_g, pd_bf, a_src_bf, a_dst, n);

    const int axBlocks = (E + 255) / 256;   // 3125
    edge_part<<<EPART_BLOCKS + axBlocks, 256, 0, stream>>>(
        src, dst, feat_edge, w_e0, w_e1, a_src_bf, gcnt, part, ax, E, nbuck);

    bucket_agg<<<nbuck * SLICES, 256, 0, stream>>>(
        part, gcnt, ax, a_dst, prop_i8, scale_g, pd_bf, out, n);
}